// Round 2
// baseline (105.301 us; speedup 1.0000x reference)
//
#include <hip/hip_runtime.h>

// ---------------- ws float offsets ----------------
enum : int {
  WS_B1 = 0,        // 64x64   S1s@s2_w
  WS_A2 = 4096,     // 2x64    (se_w@S1e)@s2_w
  WS_K1 = 4224,     // 64      k0@s2_w
  WS_NW = 4288,     // 64x64   n1_w@n2_w
  WS_NB = 8384,     // 64      n1_b@n2_w + n2_b
  WS_C1 = 8448,     // 64x64   2*A1@NW
  WS_C2 = 12544,    // 2x64    -2*A2@NW
  WS_D1 = 12672,    // 64x64   E1r@e2_w
  WS_D2 = 16768,    // 64x64   E1s@e2_w
  WS_D0 = 20864,    // 64      2*(e1_b@e2_w + e2_b)
  WS_H1 = 20928,    // 64x128  G1@f1_w
  WS_H2 = 29120,    // 2x128   G2@f1_w
  WS_H3 = 29376,    // 32x128  per-batch bias into f1 layer
  WS_M  = 33472,    // 2x128   se_w@S1e
  WS_K0 = 33728,    // 128     se_b@S1e + s1_b
  WS_A1 = 33856,    // 64x64   S1r@s2_w
  WS_G1 = 37952,    // 64x64   2*C1@D1
  WS_G2 = 42048,    // 2x64    2*C2@D1
  WS_END = 42176
};

// 4 consecutive output columns: c[j] = sum_k a[k] * b[k*bs + j]
__device__ __forceinline__ void dotq(const float* a, const float* b, int bs, int n, float c[4]){
  float c0=0.f,c1=0.f,c2=0.f,c3=0.f;
  #pragma unroll 4
  for (int k=0;k<n;++k){
    float av = a[k];
    const float* bp = b + k*bs;
    c0 = fmaf(av, bp[0], c0);
    c1 = fmaf(av, bp[1], c1);
    c2 = fmaf(av, bp[2], c2);
    c3 = fmaf(av, bp[3], c3);
  }
  c[0]=c0;c[1]=c1;c[2]=c2;c[3]=c3;
}

// ---------------- K1a: independent weight products ----------------
__global__ __launch_bounds__(256) void k_wprep0(
    const float* __restrict__ se_w, const float* __restrict__ se_b,
    const float* __restrict__ s1_w, const float* __restrict__ s1_b,
    const float* __restrict__ s2_w,
    const float* __restrict__ n1_w, const float* __restrict__ n1_b,
    const float* __restrict__ n2_w, const float* __restrict__ n2_b,
    const float* __restrict__ e1_w, const float* __restrict__ e1_b,
    const float* __restrict__ e2_w, const float* __restrict__ e2_b,
    float* __restrict__ ws)
{
  int q = blockIdx.x * 256 + threadIdx.x;
  float c[4];
  if (q < 64) {            // M[2][128] = se_w @ S1e   (S1e = s1_w rows 128..191)
    int r = q >> 5, c4 = (q & 31) * 4;
    dotq(se_w + r * 64, s1_w + 16384 + c4, 128, 64, c);
    for (int j = 0; j < 4; ++j) ws[WS_M + r * 128 + c4 + j] = c[j];
  } else if (q < 96) {     // k0 = se_b @ S1e + s1_b
    int c4 = (q - 64) * 4;
    dotq(se_b, s1_w + 16384 + c4, 128, 64, c);
    for (int j = 0; j < 4; ++j) ws[WS_K0 + c4 + j] = c[j] + s1_b[c4 + j];
  } else if (q < 1120) {   // A1 = S1r @ s2_w
    int i = q - 96, a = i >> 4, b4 = (i & 15) * 4;
    dotq(s1_w + a * 128, s2_w + b4, 64, 128, c);
    for (int j = 0; j < 4; ++j) ws[WS_A1 + a * 64 + b4 + j] = c[j];
  } else if (q < 2144) {   // B1 = S1s @ s2_w
    int i = q - 1120, a = i >> 4, b4 = (i & 15) * 4;
    dotq(s1_w + (64 + a) * 128, s2_w + b4, 64, 128, c);
    for (int j = 0; j < 4; ++j) ws[WS_B1 + a * 64 + b4 + j] = c[j];
  } else if (q < 3168) {   // NW = n1_w @ n2_w
    int i = q - 2144, a = i >> 4, b4 = (i & 15) * 4;
    dotq(n1_w + a * 128, n2_w + b4, 64, 128, c);
    for (int j = 0; j < 4; ++j) ws[WS_NW + a * 64 + b4 + j] = c[j];
  } else if (q < 4192) {   // D1 = E1r @ e2_w
    int i = q - 3168, a = i >> 4, b4 = (i & 15) * 4;
    dotq(e1_w + a * 128, e2_w + b4, 64, 128, c);
    for (int j = 0; j < 4; ++j) ws[WS_D1 + a * 64 + b4 + j] = c[j];
  } else if (q < 5216) {   // D2 = E1s @ e2_w
    int i = q - 4192, a = i >> 4, b4 = (i & 15) * 4;
    dotq(e1_w + (64 + a) * 128, e2_w + b4, 64, 128, c);
    for (int j = 0; j < 4; ++j) ws[WS_D2 + a * 64 + b4 + j] = c[j];
  } else if (q < 5232) {   // nb = n1_b @ n2_w + n2_b
    int b4 = (q - 5216) * 4;
    dotq(n1_b, n2_w + b4, 64, 128, c);
    for (int j = 0; j < 4; ++j) ws[WS_NB + b4 + j] = c[j] + n2_b[b4 + j];
  } else if (q < 5248) {   // d0 = 2*(e1_b @ e2_w + e2_b)
    int b4 = (q - 5232) * 4;
    dotq(e1_b, e2_w + b4, 64, 128, c);
    for (int j = 0; j < 4; ++j) ws[WS_D0 + b4 + j] = 2.f * (c[j] + e2_b[b4 + j]);
  }
}

// ---------------- K1b: dependent product chain (single block, 256 thr) ----------------
__global__ __launch_bounds__(256) void k_wprep1(
    const float* __restrict__ s2_w, const float* __restrict__ f1_w,
    float* __restrict__ ws)
{
  int t = threadIdx.x;
  float c[4];
  // L1: A2 = M@s2_w ; k1 = k0@s2_w ; C1 = 2*A1@NW
  for (int q = t; q < 1072; q += 256) {
    if (q < 32) { int r = q >> 4, b4 = (q & 15) * 4;
      dotq(ws + WS_M + r * 128, s2_w + b4, 64, 128, c);
      for (int j = 0; j < 4; ++j) ws[WS_A2 + r * 64 + b4 + j] = c[j];
    } else if (q < 48) { int b4 = (q - 32) * 4;
      dotq(ws + WS_K0, s2_w + b4, 64, 128, c);
      for (int j = 0; j < 4; ++j) ws[WS_K1 + b4 + j] = c[j];
    } else { int i = q - 48, a = i >> 4, b4 = (i & 15) * 4;
      dotq(ws + WS_A1 + a * 64, ws + WS_NW + b4, 64, 64, c);
      for (int j = 0; j < 4; ++j) ws[WS_C1 + a * 64 + b4 + j] = 2.f * c[j];
    }
  }
  __syncthreads();
  // L2: C2 = -2*A2@NW ; G1 = 2*C1@D1
  for (int q = t; q < 1056; q += 256) {
    if (q < 32) { int r = q >> 4, b4 = (q & 15) * 4;
      dotq(ws + WS_A2 + r * 64, ws + WS_NW + b4, 64, 64, c);
      for (int j = 0; j < 4; ++j) ws[WS_C2 + r * 64 + b4 + j] = -2.f * c[j];
    } else { int i = q - 32, a = i >> 4, b4 = (i & 15) * 4;
      dotq(ws + WS_C1 + a * 64, ws + WS_D1 + b4, 64, 64, c);
      for (int j = 0; j < 4; ++j) ws[WS_G1 + a * 64 + b4 + j] = 2.f * c[j];
    }
  }
  __syncthreads();
  // L3: G2 = 2*C2@D1 ; H1 = G1@f1_w
  for (int q = t; q < 2080; q += 256) {
    if (q < 32) { int r = q >> 4, b4 = (q & 15) * 4;
      dotq(ws + WS_C2 + r * 64, ws + WS_D1 + b4, 64, 64, c);
      for (int j = 0; j < 4; ++j) ws[WS_G2 + r * 64 + b4 + j] = 2.f * c[j];
    } else { int i = q - 32, a = i >> 5, c4 = (i & 31) * 4;
      dotq(ws + WS_G1 + a * 64, f1_w + c4, 128, 64, c);
      for (int j = 0; j < 4; ++j) ws[WS_H1 + a * 128 + c4 + j] = c[j];
    }
  }
  __syncthreads();
  // L4: H2 = G2@f1_w
  for (int q = t; q < 64; q += 256) {
    int r = q >> 5, c4 = (q & 31) * 4;
    dotq(ws + WS_G2 + r * 64, f1_w + c4, 128, 64, c);
    for (int j = 0; j < 4; ++j) ws[WS_H2 + r * 128 + c4 + j] = c[j];
  }
}

// ---------------- K2: per-batch constants h3_b ----------------
__global__ __launch_bounds__(256) void k_batch(
    const float* __restrict__ h, const float* __restrict__ pos,
    const float* __restrict__ s2_b, const float* __restrict__ f1_w,
    const float* __restrict__ f1_b, float* __restrict__ ws)
{
  __shared__ float sX[64], sP[2], sv[64], sc3[64], sN[64], sg3[64], part[256];
  int b = blockIdx.x, t = threadIdx.x;
  { int k = t & 63, g = t >> 6; float s = 0.f;
    for (int j = g * 32; j < g * 32 + 32; ++j) s += h[(b * 128 + j) * 64 + k];
    part[t] = s; }
  __syncthreads();
  if (t < 64) sX[t] = (part[t] + part[64 + t]) + (part[128 + t] + part[192 + t]);
  else if (t < 66) { int cc = t - 64; float s = 0.f;
    for (int j = 0; j < 128; ++j) s += pos[(b * 128 + j) * 2 + cc];
    sP[cc] = s; }
  __syncthreads();
  if (t < 64) {  // v = (X@B1 + P@A2)/64 + 2*k1 + 2*s2_b
    float acc = 0.f;
    for (int k = 0; k < 64; ++k) acc = fmaf(sX[k], ws[WS_B1 + k * 64 + t], acc);
    acc += sP[0] * ws[WS_A2 + t] + sP[1] * ws[WS_A2 + 64 + t];
    sv[t] = acc * (1.f / 64.f) + 2.f * ws[WS_K1 + t] + 2.f * s2_b[t];
  }
  __syncthreads();
  if (t < 64) {  // c3 = v@NW + nb
    float acc = 0.f;
    for (int k = 0; k < 64; ++k) acc = fmaf(sv[k], ws[WS_NW + k * 64 + t], acc);
    sc3[t] = acc + ws[WS_NB + t];
  }
  __syncthreads();
  if (t < 64) {  // Nbar = X@C1 + P@C2 + 128*c3
    float acc = 0.f;
    for (int k = 0; k < 64; ++k) acc = fmaf(sX[k], ws[WS_C1 + k * 64 + t], acc);
    sN[t] = acc + sP[0] * ws[WS_C2 + t] + sP[1] * ws[WS_C2 + 64 + t] + 128.f * sc3[t];
  }
  __syncthreads();
  if (t < 64) {  // g3 = 2*c3@D1 + Nbar@D2/64 + d0
    float a1 = 0.f, a2 = 0.f;
    for (int k = 0; k < 64; ++k) a1 = fmaf(sc3[k], ws[WS_D1 + k * 64 + t], a1);
    for (int k = 0; k < 64; ++k) a2 = fmaf(sN[k], ws[WS_D2 + k * 64 + t], a2);
    sg3[t] = 2.f * a1 + a2 * (1.f / 64.f) + ws[WS_D0 + t];
  }
  __syncthreads();
  if (t < 128) { // h3 = g3@f1_w + f1_b
    float acc = 0.f;
    for (int k = 0; k < 64; ++k) acc = fmaf(sg3[k], f1_w[k * 128 + t], acc);
    ws[WS_H3 + b * 128 + t] = acc + f1_b[t];
  }
}

// ---------------- K3: per-node fused MLP (LDS ~46 KB) ----------------
__global__ __launch_bounds__(256) void k_main(
    const float* __restrict__ h, const float* __restrict__ pos,
    const float* __restrict__ f2_w, const float* __restrict__ f2_b,
    const float* __restrict__ ws, float* __restrict__ out)
{
  __shared__ __align__(16) float lH1[64 * 128];  // [k][d]  32 KB
  __shared__ __align__(16) float lH2[2 * 128];   // 1 KB
  __shared__ float lh3[128], lf2b[64];
  __shared__ __align__(16) float lx[16 * 64];    // [n][k]  4 KB
  __shared__ float lp[16 * 2];
  __shared__ __align__(16) float lh1[16 * 128];  // [n][k]  8 KB
  int blk = blockIdx.x, t = threadIdx.x;
  int b = blk >> 3, j0 = (blk & 7) * 16;
  for (int i = t; i < 2048; i += 256) ((float4*)lH1)[i] = ((const float4*)(ws + WS_H1))[i];
  for (int i = t; i < 64; i += 256) ((float4*)lH2)[i] = ((const float4*)(ws + WS_H2))[i];
  if (t < 128) lh3[t] = ws[WS_H3 + b * 128 + t];
  if (t < 64) lf2b[t] = f2_b[t];
  for (int i = t; i < 256; i += 256) ((float4*)lx)[i] = ((const float4*)(h + (size_t)(b * 128 + j0) * 64))[i];
  if (t < 32) lp[t] = pos[(b * 128 + j0) * 2 + t];
  __syncthreads();
  // h1 = relu(x@H1 + p@H2 + h3)
  {
    int d = t & 127, g = t >> 7, n0 = g * 8;
    float acc[8];
    #pragma unroll
    for (int i = 0; i < 8; ++i)
      acc[i] = lh3[d] + lp[(n0 + i) * 2] * lH2[d] + lp[(n0 + i) * 2 + 1] * lH2[128 + d];
    for (int k = 0; k < 64; k += 4) {
      float h0 = lH1[k * 128 + d], h1v = lH1[(k + 1) * 128 + d],
            h2v = lH1[(k + 2) * 128 + d], h3v = lH1[(k + 3) * 128 + d];
      #pragma unroll
      for (int i = 0; i < 8; ++i) {
        float4 xv = *(const float4*)&lx[(n0 + i) * 64 + k];
        acc[i] = fmaf(xv.x, h0, fmaf(xv.y, h1v, fmaf(xv.z, h2v, fmaf(xv.w, h3v, acc[i]))));
      }
    }
    #pragma unroll
    for (int i = 0; i < 8; ++i) lh1[(n0 + i) * 128 + d] = fmaxf(acc[i], 0.f);
  }
  __syncthreads();
  // out = relu(h1@f2_w + f2_b); f2_w read straight from global (32 KB, L1/L2-resident)
  {
    int d = t & 63, g = t >> 6, n0 = g * 4;
    float acc[4];
    #pragma unroll
    for (int i = 0; i < 4; ++i) acc[i] = lf2b[d];
    for (int k = 0; k < 128; k += 4) {
      float f0 = f2_w[k * 64 + d], f1v = f2_w[(k + 1) * 64 + d],
            f2v = f2_w[(k + 2) * 64 + d], f3v = f2_w[(k + 3) * 64 + d];
      #pragma unroll
      for (int i = 0; i < 4; ++i) {
        float4 hv = *(const float4*)&lh1[(n0 + i) * 128 + k];
        acc[i] = fmaf(hv.x, f0, fmaf(hv.y, f1v, fmaf(hv.z, f2v, fmaf(hv.w, f3v, acc[i]))));
      }
    }
    #pragma unroll
    for (int i = 0; i < 4; ++i)
      out[(size_t)(b * 128 + j0 + n0 + i) * 64 + d] = fmaxf(acc[i], 0.f);
  }
}

extern "C" void kernel_launch(void* const* d_in, const int* in_sizes, int n_in,
                              void* d_out, int out_size, void* d_ws, size_t ws_size,
                              hipStream_t stream) {
  const float* h    = (const float*)d_in[0];
  const float* pos  = (const float*)d_in[1];
  const float* se_w = (const float*)d_in[2];
  const float* se_b = (const float*)d_in[3];
  const float* s1_w = (const float*)d_in[4];
  const float* s1_b = (const float*)d_in[5];
  const float* s2_w = (const float*)d_in[6];
  const float* s2_b = (const float*)d_in[7];
  const float* n1_w = (const float*)d_in[8];
  const float* n1_b = (const float*)d_in[9];
  const float* n2_w = (const float*)d_in[10];
  const float* n2_b = (const float*)d_in[11];
  const float* e1_w = (const float*)d_in[12];
  const float* e1_b = (const float*)d_in[13];
  const float* e2_w = (const float*)d_in[14];
  const float* e2_b = (const float*)d_in[15];
  const float* f1_w = (const float*)d_in[16];
  const float* f1_b = (const float*)d_in[17];
  const float* f2_w = (const float*)d_in[18];
  const float* f2_b = (const float*)d_in[19];
  float* ws = (float*)d_ws;
  float* out = (float*)d_out;

  hipLaunchKernelGGL(k_wprep0, dim3(21), dim3(256), 0, stream,
                     se_w, se_b, s1_w, s1_b, s2_w, n1_w, n1_b, n2_w, n2_b,
                     e1_w, e1_b, e2_w, e2_b, ws);
  hipLaunchKernelGGL(k_wprep1, dim3(1), dim3(256), 0, stream, s2_w, f1_w, ws);
  hipLaunchKernelGGL(k_batch, dim3(32), dim3(256), 0, stream, h, pos, s2_b, f1_w, f1_b, ws);
  hipLaunchKernelGGL(k_main, dim3(256), dim3(256), 0, stream, h, pos, f2_w, f2_b, ws, out);
}

// Round 4
// 32.913 us; speedup vs baseline: 3.1994x; 3.1994x over previous
//
#include <hip/hip_runtime.h>

// ---------------- ws float offsets ----------------
enum : int {
  WS_A1  = 0,      // 64x64  S1r@s2_w
  WS_B1  = 4096,   // 64x64  S1s@s2_w
  WS_SE2 = 8192,   // 64x64  S1e@s2_w
  WS_NW  = 12288,  // 64x64  n1_w@n2_w
  WS_D1  = 16384,  // 64x64  E1r@e2_w
  WS_D2  = 20480,  // 64x64  E1s@e2_w
  WS_K0  = 24576,  // 128    se_b@S1e + s1_b
  WS_NB  = 24704,  // 64     n1_b@n2_w + n2_b
  WS_D0  = 24768,  // 64     2*(e1_b@e2_w + e2_b)
  WS_P1  = 24832,  // 64x64  A1@NW          (C1 = 2*P1)
  WS_P2  = 28928,  // 64x128 D1@f1_w
  WS_A2  = 37120,  // 2x64   se_w@SE2
  WS_K1  = 37248,  // 64     k0@s2_w
  WS_C2  = 37312,  // 2x64   -2*A2@NW
  WS_H1  = 37440,  // 64x128 4*P1@P2
  WS_H2  = 45632,  // 2x128  2*C2@P2
  WS_H3  = 45888,  // 32x128 per-batch bias into f1 layer
  WS_END = 49984
};

// 4 rows x 1 col dot: c[i] = sum_k a[i*as + k] * b[k*BS]
template<int N, int BS>
__device__ __forceinline__ void dot4row(const float* __restrict__ a, int as,
                                        const float* __restrict__ b, float c[4]){
  float c0=0.f,c1=0.f,c2=0.f,c3=0.f;
  #pragma unroll
  for (int k=0;k<N;++k){
    float bv = b[k*BS];
    c0 = fmaf(a[k],        bv, c0);
    c1 = fmaf(a[as+k],     bv, c1);
    c2 = fmaf(a[2*as+k],   bv, c2);
    c3 = fmaf(a[3*as+k],   bv, c3);
  }
  c[0]=c0;c[1]=c1;c[2]=c2;c[3]=c3;
}

template<int N, int BS>
__device__ __forceinline__ float dot1(const float* __restrict__ a, const float* __restrict__ b){
  float c = 0.f;
  #pragma unroll
  for (int k=0;k<N;++k) c = fmaf(a[k], b[k*BS], c);
  return c;
}

// ---------------- K1: level-0 products (25 blocks x 256) ----------------
// blocks 0-3 A1, 4-7 B1, 8-11 SE2, 12-15 NW, 16-19 D1, 20-23 D2, 24 smalls
__global__ __launch_bounds__(256) void k_lvl0(
    const float* __restrict__ se_b,
    const float* __restrict__ s1_w, const float* __restrict__ s1_b,
    const float* __restrict__ s2_w,
    const float* __restrict__ n1_w, const float* __restrict__ n1_b,
    const float* __restrict__ n2_w, const float* __restrict__ n2_b,
    const float* __restrict__ e1_w, const float* __restrict__ e1_b,
    const float* __restrict__ e2_w, const float* __restrict__ e2_b,
    float* __restrict__ ws)
{
  int blk = blockIdx.x, t = threadIdx.x;
  if (blk < 24) {
    int which = blk >> 2, lb = blk & 3;
    int col = t & 63, row = lb * 16 + (t >> 6) * 4;
    const float* a; const float* b; float* o;
    switch (which) {
      case 0: a = s1_w + row * 128;         b = s2_w + col; o = ws + WS_A1;  break;
      case 1: a = s1_w + (64 + row) * 128;  b = s2_w + col; o = ws + WS_B1;  break;
      case 2: a = s1_w + (128 + row) * 128; b = s2_w + col; o = ws + WS_SE2; break;
      case 3: a = n1_w + row * 128;         b = n2_w + col; o = ws + WS_NW;  break;
      case 4: a = e1_w + row * 128;         b = e2_w + col; o = ws + WS_D1;  break;
      default:a = e1_w + (64 + row) * 128;  b = e2_w + col; o = ws + WS_D2;  break;
    }
    float c[4];
    dot4row<128, 64>(a, 128, b, c);
    #pragma unroll
    for (int i = 0; i < 4; ++i) o[(row + i) * 64 + col] = c[i];
  } else {
    if (t < 128) {            // k0[t] = se_b@S1e + s1_b
      ws[WS_K0 + t] = dot1<64, 128>(se_b, s1_w + 128 * 128 + t) + s1_b[t];
    } else if (t < 192) {     // nb = n1_b@n2_w + n2_b
      int c = t - 128;
      ws[WS_NB + c] = dot1<128, 64>(n1_b, n2_w + c) + n2_b[c];
    } else {                  // d0 = 2*(e1_b@e2_w + e2_b)
      int c = t - 192;
      ws[WS_D0 + c] = 2.f * (dot1<128, 64>(e1_b, e2_w + c) + e2_b[c]);
    }
  }
}

// ---------------- K2: level-1 products (13 blocks x 256) ----------------
// blocks 0-3: P1 = A1@NW ; 4-11: P2 = D1@f1_w ; 12: A2,K1 then C2
__global__ __launch_bounds__(256) void k_lvl1(
    const float* __restrict__ se_w, const float* __restrict__ s2_w,
    const float* __restrict__ f1_w, float* __restrict__ ws)
{
  int blk = blockIdx.x, t = threadIdx.x;
  if (blk < 4) {            // P1[row][col] = sum_k A1[row][k]*NW[k][col]
    int col = t & 63, row = blk * 16 + (t >> 6) * 4;
    float c[4];
    dot4row<64, 64>(ws + WS_A1 + row * 64, 64, ws + WS_NW + col, c);
    #pragma unroll
    for (int i = 0; i < 4; ++i) ws[WS_P1 + (row + i) * 64 + col] = c[i];
  } else if (blk < 12) {    // P2[row][c] = sum_k D1[row][k]*f1_w[k][c]
    int c128 = t & 127, row = (blk - 4) * 8 + (t >> 7) * 4;
    float c[4];
    dot4row<64, 128>(ws + WS_D1 + row * 64, 64, f1_w + c128, c);
    #pragma unroll
    for (int i = 0; i < 4; ++i) ws[WS_P2 + (row + i) * 128 + c128] = c[i];
  } else {                  // special: A2, K1, then C2 (needs A2)
    __shared__ float sA2[128];
    if (t < 128) {          // A2[r][c] = sum_k se_w[r][k]*SE2[k][c]
      int r = t >> 6, c = t & 63;
      float v = dot1<64, 64>(se_w + r * 64, ws + WS_SE2 + c);
      sA2[t] = v;
      ws[WS_A2 + t] = v;
    } else if (t < 192) {   // K1[c] = sum_k k0[k]*s2_w[k][c]
      int c = t - 128;
      ws[WS_K1 + c] = dot1<128, 64>(ws + WS_K0, s2_w + c);
    }
    __syncthreads();
    if (t < 128) {          // C2[r][c] = -2*sum_k A2[r][k]*NW[k][c]
      int r = t >> 6, c = t & 63;
      ws[WS_C2 + t] = -2.f * dot1<64, 64>(sA2 + r * 64, ws + WS_NW + c);
    }
  }
}

// ---------------- K3: level-2 + per-batch (41 blocks x 256) ----------------
// blocks 0-7: H1 = 4*P1@P2 ; 8: H2 = 2*C2@P2 ; 9-40: per-batch H3
__global__ __launch_bounds__(256) void k_lvl2(
    const float* __restrict__ h, const float* __restrict__ pos,
    const float* __restrict__ s2_b, const float* __restrict__ f1_w,
    const float* __restrict__ f1_b, float* __restrict__ ws)
{
  int blk = blockIdx.x, t = threadIdx.x;
  if (blk < 8) {            // H1[row][c] = 4*sum_k P1[row][k]*P2[k][c]
    int c128 = t & 127, row = blk * 8 + (t >> 7) * 4;
    float c[4];
    dot4row<64, 128>(ws + WS_P1 + row * 64, 64, ws + WS_P2 + c128, c);
    #pragma unroll
    for (int i = 0; i < 4; ++i) ws[WS_H1 + (row + i) * 128 + c128] = 4.f * c[i];
    return;
  }
  if (blk == 8) {           // H2[r][c] = 2*sum_k C2[r][k]*P2[k][c]
    int r = t >> 7, c = t & 127;
    ws[WS_H2 + t] = 2.f * dot1<64, 128>(ws + WS_C2 + r * 64, ws + WS_P2 + c);
    return;
  }
  // ---- per-batch chain ----
  __shared__ float sX[64], sP[2], sv[64], sc3[64], sN[64], sg3[64], part[256];
  int b = blk - 9;
  { int k = t & 63, g = t >> 6; float s = 0.f;
    #pragma unroll 8
    for (int j = g * 32; j < g * 32 + 32; ++j) s += h[(b * 128 + j) * 64 + k];
    part[t] = s; }
  __syncthreads();
  if (t < 64) sX[t] = (part[t] + part[64 + t]) + (part[128 + t] + part[192 + t]);
  else if (t < 66) { int cc = t - 64; float s = 0.f;
    #pragma unroll 16
    for (int j = 0; j < 128; ++j) s += pos[(b * 128 + j) * 2 + cc];
    sP[cc] = s; }
  __syncthreads();
  if (t < 64) {  // v = (X@B1 + P@A2)/64 + 2*K1 + 2*s2_b
    float acc = dot1<64, 64>(sX, ws + WS_B1 + t);
    acc += sP[0] * ws[WS_A2 + t] + sP[1] * ws[WS_A2 + 64 + t];
    sv[t] = acc * (1.f / 64.f) + 2.f * ws[WS_K1 + t] + 2.f * s2_b[t];
  }
  __syncthreads();
  if (t < 64) {  // c3 = v@NW + nb
    sc3[t] = dot1<64, 64>(sv, ws + WS_NW + t) + ws[WS_NB + t];
  }
  __syncthreads();
  if (t < 64) {  // Nbar = 2*X@P1 + P@C2 + 128*c3
    float acc = 2.f * dot1<64, 64>(sX, ws + WS_P1 + t);
    sN[t] = acc + sP[0] * ws[WS_C2 + t] + sP[1] * ws[WS_C2 + 64 + t] + 128.f * sc3[t];
  }
  __syncthreads();
  if (t < 64) {  // g3 = 2*c3@D1 + Nbar@D2/64 + d0
    float a1 = dot1<64, 64>(sc3, ws + WS_D1 + t);
    float a2 = dot1<64, 64>(sN, ws + WS_D2 + t);
    sg3[t] = 2.f * a1 + a2 * (1.f / 64.f) + ws[WS_D0 + t];
  }
  __syncthreads();
  if (t < 128) { // h3 = g3@f1_w + f1_b
    ws[WS_H3 + b * 128 + t] = dot1<64, 128>(sg3, f1_w + t) + f1_b[t];
  }
}

// ---------------- K4: per-node fused MLP (LDS ~46 KB) ----------------
__global__ __launch_bounds__(256) void k_main(
    const float* __restrict__ h, const float* __restrict__ pos,
    const float* __restrict__ f2_w, const float* __restrict__ f2_b,
    const float* __restrict__ ws, float* __restrict__ out)
{
  __shared__ __align__(16) float lH1[64 * 128];  // [k][d]  32 KB
  __shared__ __align__(16) float lH2[2 * 128];
  __shared__ float lh3[128], lf2b[64];
  __shared__ __align__(16) float lx[16 * 64];    // [n][k]
  __shared__ float lp[16 * 2];
  __shared__ __align__(16) float lh1[16 * 128];  // [n][k]
  int blk = blockIdx.x, t = threadIdx.x;
  int b = blk >> 3, j0 = (blk & 7) * 16;
  for (int i = t; i < 2048; i += 256) ((float4*)lH1)[i] = ((const float4*)(ws + WS_H1))[i];
  for (int i = t; i < 64; i += 256) ((float4*)lH2)[i] = ((const float4*)(ws + WS_H2))[i];
  if (t < 128) lh3[t] = ws[WS_H3 + b * 128 + t];
  if (t < 64) lf2b[t] = f2_b[t];
  { ((float4*)lx)[t] = ((const float4*)(h + (size_t)(b * 128 + j0) * 64))[t]; }
  if (t < 32) lp[t] = pos[(b * 128 + j0) * 2 + t];
  __syncthreads();
  // h1 = relu(x@H1 + p@H2 + h3)
  {
    int d = t & 127, g = t >> 7, n0 = g * 8;
    float acc[8];
    #pragma unroll
    for (int i = 0; i < 8; ++i)
      acc[i] = lh3[d] + lp[(n0 + i) * 2] * lH2[d] + lp[(n0 + i) * 2 + 1] * lH2[128 + d];
    #pragma unroll 4
    for (int k = 0; k < 64; k += 4) {
      float h0 = lH1[k * 128 + d], h1v = lH1[(k + 1) * 128 + d],
            h2v = lH1[(k + 2) * 128 + d], h3v = lH1[(k + 3) * 128 + d];
      #pragma unroll
      for (int i = 0; i < 8; ++i) {
        float4 xv = *(const float4*)&lx[(n0 + i) * 64 + k];
        acc[i] = fmaf(xv.x, h0, fmaf(xv.y, h1v, fmaf(xv.z, h2v, fmaf(xv.w, h3v, acc[i]))));
      }
    }
    #pragma unroll
    for (int i = 0; i < 8; ++i) lh1[(n0 + i) * 128 + d] = fmaxf(acc[i], 0.f);
  }
  __syncthreads();
  // out = relu(h1@f2_w + f2_b); f2_w read from global (32 KB, L2-resident)
  {
    int d = t & 63, g = t >> 6, n0 = g * 4;
    float acc[4];
    #pragma unroll
    for (int i = 0; i < 4; ++i) acc[i] = lf2b[d];
    #pragma unroll 4
    for (int k = 0; k < 128; k += 4) {
      float f0 = f2_w[k * 64 + d], f1v = f2_w[(k + 1) * 64 + d],
            f2v = f2_w[(k + 2) * 64 + d], f3v = f2_w[(k + 3) * 64 + d];
      #pragma unroll
      for (int i = 0; i < 4; ++i) {
        float4 hv = *(const float4*)&lh1[(n0 + i) * 128 + k];
        acc[i] = fmaf(hv.x, f0, fmaf(hv.y, f1v, fmaf(hv.z, f2v, fmaf(hv.w, f3v, acc[i]))));
      }
    }
    #pragma unroll
    for (int i = 0; i < 4; ++i)
      out[(size_t)(b * 128 + j0 + n0 + i) * 64 + d] = fmaxf(acc[i], 0.f);
  }
}

extern "C" void kernel_launch(void* const* d_in, const int* in_sizes, int n_in,
                              void* d_out, int out_size, void* d_ws, size_t ws_size,
                              hipStream_t stream) {
  const float* h    = (const float*)d_in[0];
  const float* pos  = (const float*)d_in[1];
  const float* se_w = (const float*)d_in[2];
  const float* se_b = (const float*)d_in[3];
  const float* s1_w = (const float*)d_in[4];
  const float* s1_b = (const float*)d_in[5];
  const float* s2_w = (const float*)d_in[6];
  const float* s2_b = (const float*)d_in[7];
  const float* n1_w = (const float*)d_in[8];
  const float* n1_b = (const float*)d_in[9];
  const float* n2_w = (const float*)d_in[10];
  const float* n2_b = (const float*)d_in[11];
  const float* e1_w = (const float*)d_in[12];
  const float* e1_b = (const float*)d_in[13];
  const float* e2_w = (const float*)d_in[14];
  const float* e2_b = (const float*)d_in[15];
  const float* f1_w = (const float*)d_in[16];
  const float* f1_b = (const float*)d_in[17];
  const float* f2_w = (const float*)d_in[18];
  const float* f2_b = (const float*)d_in[19];
  float* ws = (float*)d_ws;
  float* out = (float*)d_out;

  hipLaunchKernelGGL(k_lvl0, dim3(25), dim3(256), 0, stream,
                     se_b, s1_w, s1_b, s2_w, n1_w, n1_b, n2_w, n2_b,
                     e1_w, e1_b, e2_w, e2_b, ws);
  hipLaunchKernelGGL(k_lvl1, dim3(13), dim3(256), 0, stream, se_w, s2_w, f1_w, ws);
  hipLaunchKernelGGL(k_lvl2, dim3(41), dim3(256), 0, stream, h, pos, s2_b, f1_w, f1_b, ws);
  hipLaunchKernelGGL(k_main, dim3(256), dim3(256), 0, stream, h, pos, f2_w, f2_b, ws, out);
}